// Round 1
// baseline (1895.336 us; speedup 1.0000x reference)
//
#include <hip/hip_runtime.h>
#include <hip/hip_bf16.h>

// Problem constants
#define BB   128
#define DV   2048
#define SS   196
#define DQ   2048
#define DA   1200
#define DAP  1280      // DA padded to 10*128 MFMA n-tiles
#define GG   4
#define DH   2048
#define NANS 3000
#define MROWS (BB*SS)  // 25088 = 196 * 128 exactly

typedef __attribute__((ext_vector_type(8))) short bf16x8;
typedef __attribute__((ext_vector_type(4))) float f32x4;

__device__ __forceinline__ float fast_tanh(float x) {
    // tanh(x) = 1 - 2/(exp(2x)+1); exact algebra, err ~1e-6 from v_exp/v_rcp
    float e = __expf(2.0f * x);
    return 1.0f - 2.0f * __builtin_amdgcn_rcpf(e + 1.0f);
}

__device__ __forceinline__ void async_copy16(const void* gsrc, void* ldst) {
    __builtin_amdgcn_global_load_lds(
        (const __attribute__((address_space(1))) void*)gsrc,
        (__attribute__((address_space(3))) void*)ldst, 16, 0, 0);
}

// ---------------------------------------------------------------------------
// K0a: v [B][DV][S] fp32 -> v_t [(b*S+s)][DV] bf16   (row-major, K-contiguous)
// ---------------------------------------------------------------------------
__global__ __launch_bounds__(256) void transpose_v(const float* __restrict__ v,
                                                   __hip_bfloat16* __restrict__ vt) {
    __shared__ float tile[64][65];
    const int b  = blockIdx.z;
    const int c0 = blockIdx.x * 64;
    const int s0 = blockIdx.y * 64;
    const int t  = threadIdx.x;
    const int col  = t & 63;
    const int rowb = t >> 6;
    const float* src = v + (size_t)b * DV * SS;
#pragma unroll
    for (int i = 0; i < 16; ++i) {
        int c = rowb + i * 4;
        int s = s0 + col;
        tile[c][col] = (s < SS) ? src[(size_t)(c0 + c) * SS + s] : 0.f;
    }
    __syncthreads();
#pragma unroll
    for (int i = 0; i < 16; ++i) {
        int sl = rowb + i * 4;
        int s  = s0 + sl;
        if (s < SS)
            vt[((size_t)b * SS + s) * DV + c0 + col] = __float2bfloat16(tile[col][sl]);
    }
}

// ---------------------------------------------------------------------------
// K0b: Wv [DV][DA] fp32 -> wvt [DAP][DV] bf16 (B^T layout), pad rows zeroed
// ---------------------------------------------------------------------------
__global__ __launch_bounds__(256) void transpose_w(const float* __restrict__ Wv,
                                                   __hip_bfloat16* __restrict__ wvt) {
    __shared__ float tile[64][65];
    const int d0 = blockIdx.x * 64;   // 20 tiles over DAP
    const int c0 = blockIdx.y * 64;   // 32 tiles over DV
    const int t  = threadIdx.x;
    const int col  = t & 63;
    const int rowb = t >> 6;
#pragma unroll
    for (int i = 0; i < 16; ++i) {
        int c = rowb + i * 4;
        int d = d0 + col;
        tile[c][col] = (d < DA) ? Wv[(size_t)(c0 + c) * DA + d] : 0.f;
    }
    __syncthreads();
#pragma unroll
    for (int i = 0; i < 16; ++i) {
        int dl = rowb + i * 4;
        wvt[(size_t)(d0 + dl) * DV + c0 + col] = __float2bfloat16(tile[col][dl]);
    }
}

__global__ void pad_bv(const float* __restrict__ bv, float* __restrict__ bvp) {
    int i = blockIdx.x * 256 + threadIdx.x;
    if (i < DAP) bvp[i] = (i < DA) ? bv[i] : 0.f;
}

// ---------------------------------------------------------------------------
// Small fp32 GEMM: C[M,N] = epilogue(A[M,K] * B[K,N] + bias)
// BM=64, BN=64, BK=32, 256 threads, 4x4 per-thread tile.
// MODE 0: plain+bias (classifier) | MODE 1: tanh (q branches; pad cols -> 0)
// MODE 2: tanh(acc+bf) * aux then tanh  (glimpse fusion; A/B offset by g)
// ---------------------------------------------------------------------------
template <int MODE>
__global__ __launch_bounds__(256) void gemm_small(
    const float* __restrict__ A, int lda,
    const float* __restrict__ Bm, int ldb,
    const float* __restrict__ bias,
    float* __restrict__ C, int ldc,
    int N, int Nreal, int K,
    const float* __restrict__ aux) {
    __shared__ float As[64][33];
    __shared__ float Bs[32][68];
    const int t  = threadIdx.x;
    const int tx = t & 15, ty = t >> 4;
    const int n0 = blockIdx.x * 64, m0 = blockIdx.y * 64;

    const float* Aeff = A;
    const float* Beff = Bm;
    int ncol0 = n0;
    if (MODE == 2) {
        int g = n0 >> 9;                        // 512 cols per glimpse, 64|512
        Aeff  = A + g * 2048;                   // v_att[b][g][:]
        Beff  = Bm + (size_t)g * K * ldb;       // Wf[g]
        ncol0 = n0 & 511;
    }

    float acc[4][4] = {};
    for (int k0 = 0; k0 < K; k0 += 32) {
        {
            int kk = t & 31, row = t >> 5;
#pragma unroll
            for (int i = 0; i < 8; ++i) {
                int m = row + i * 8;
                As[m][kk] = Aeff[(size_t)(m0 + m) * lda + k0 + kk];
            }
        }
        {
            int j = t & 63, kr = t >> 6;
#pragma unroll
            for (int i = 0; i < 8; ++i) {
                int k = kr + i * 4;
                int n = n0 + j;
                Bs[k][j] = (n < Nreal) ? Beff[(size_t)(k0 + k) * ldb + ncol0 + j] : 0.f;
            }
        }
        __syncthreads();
#pragma unroll
        for (int kk = 0; kk < 32; ++kk) {
            float b0 = Bs[kk][tx * 4 + 0], b1 = Bs[kk][tx * 4 + 1];
            float b2 = Bs[kk][tx * 4 + 2], b3 = Bs[kk][tx * 4 + 3];
#pragma unroll
            for (int i = 0; i < 4; ++i) {
                float a = As[ty * 4 + i][kk];
                acc[i][0] += a * b0; acc[i][1] += a * b1;
                acc[i][2] += a * b2; acc[i][3] += a * b3;
            }
        }
        __syncthreads();
    }
#pragma unroll
    for (int i = 0; i < 4; ++i) {
        int m = m0 + ty * 4 + i;
#pragma unroll
        for (int j = 0; j < 4; ++j) {
            int n = n0 + tx * 4 + j;
            if (n >= N) continue;
            float v = acc[i][j];
            float outv;
            if (MODE == 0) {
                outv = v + bias[n];
            } else if (MODE == 1) {
                outv = (n < Nreal) ? fast_tanh(v + bias[n]) : 0.f;
            } else {
                float xv = fast_tanh(v + bias[n]);
                outv = fast_tanh(xv * aux[(size_t)m * 2048 + n]);
            }
            C[(size_t)m * ldc + n] = outv;
        }
    }
}

// ---------------------------------------------------------------------------
// K1: big MFMA GEMM (m97 structure).
// x_att[r][d] = tanh( tanh( sum_c vt[r][c]*wvt[d][c] + bv[d] ) * qatt[b][d] )
// 128x128 tile, BK=32, 4 waves 2x2, mfma_f32_16x16x32_bf16, global_load_lds.
// M=25088=196*128 exact, N=DAP=1280=10*128 exact, K=2048 exact: no guards.
// ---------------------------------------------------------------------------
__global__ __launch_bounds__(256) void big_gemm(
    const __hip_bfloat16* __restrict__ vt,
    const __hip_bfloat16* __restrict__ wt,
    const float* __restrict__ bvp,
    const float* __restrict__ qatt,
    __hip_bfloat16* __restrict__ xatt) {
    __shared__ __hip_bfloat16 As[128 * 32];
    __shared__ __hip_bfloat16 Bs[128 * 32];
    const int t    = threadIdx.x;
    const int lane = t & 63;
    const int w    = t >> 6;
    const int wm   = w >> 1, wn = w & 1;
    const int m0   = blockIdx.x * 128;
    const int n0   = blockIdx.y * 128;

    f32x4 acc[4][4];
#pragma unroll
    for (int i = 0; i < 4; ++i)
#pragma unroll
        for (int j = 0; j < 4; ++j) acc[i][j] = (f32x4){0.f, 0.f, 0.f, 0.f};

    const int lrow = lane >> 2;        // 4 lanes per 64B row
    const int lcol = (lane & 3) * 8;   // bf16 elem offset within BK

    for (int k0 = 0; k0 < DV; k0 += 32) {
        __syncthreads();
#pragma unroll
        for (int i = 0; i < 2; ++i) {
            int r = w * 32 + i * 16;   // wave-uniform LDS segment base
            async_copy16(vt + (size_t)(m0 + r + lrow) * DV + k0 + lcol, (void*)(As + r * 32));
            async_copy16(wt + (size_t)(n0 + r + lrow) * DV + k0 + lcol, (void*)(Bs + r * 32));
        }
        __syncthreads();
        bf16x8 a[4], b[4];
        const int ko   = (lane >> 4) * 8;
        const int ra   = (wm * 64 + (lane & 15)) * 32 + ko;
        const int rb   = (wn * 64 + (lane & 15)) * 32 + ko;
#pragma unroll
        for (int mi = 0; mi < 4; ++mi) a[mi] = *(const bf16x8*)(As + ra + mi * 16 * 32);
#pragma unroll
        for (int ni = 0; ni < 4; ++ni) b[ni] = *(const bf16x8*)(Bs + rb + ni * 16 * 32);
#pragma unroll
        for (int mi = 0; mi < 4; ++mi)
#pragma unroll
            for (int ni = 0; ni < 4; ++ni)
                acc[mi][ni] = __builtin_amdgcn_mfma_f32_16x16x32_bf16(a[mi], b[ni], acc[mi][ni], 0, 0, 0);
    }

    // Epilogue: C/D layout col=lane&15, row=(lane>>4)*4+reg  [m89/m91 verified]
    const int colb = n0 + wn * 64 + (lane & 15);
    float bvv[4];
#pragma unroll
    for (int ni = 0; ni < 4; ++ni) bvv[ni] = bvp[colb + ni * 16];
#pragma unroll
    for (int mi = 0; mi < 4; ++mi) {
#pragma unroll
        for (int r = 0; r < 4; ++r) {
            int row = m0 + wm * 64 + mi * 16 + ((lane >> 4) << 2) + r;
            unsigned bb = (unsigned)row / 196u;
            const float* qrow = qatt + (size_t)bb * DAP;
            __hip_bfloat16* orow = xatt + (size_t)row * DAP;
#pragma unroll
            for (int ni = 0; ni < 4; ++ni) {
                int d = colb + ni * 16;
                float xv = fast_tanh(acc[mi][ni][r] + bvv[ni]);
                float xa = fast_tanh(xv * qrow[d]);
                orow[d] = __float2bfloat16(xa);
            }
        }
    }
}

// ---------------------------------------------------------------------------
// K2: per-batch scores -> softmax over s -> glimpse pooling.
// One block per b. ba omitted: constant-over-s shifts cancel in softmax.
// ---------------------------------------------------------------------------
__global__ __launch_bounds__(256) void att_pool(
    const __hip_bfloat16* __restrict__ xatt,
    const float* __restrict__ Wa,
    const __hip_bfloat16* __restrict__ vt,
    float* __restrict__ vatt) {
    __shared__ __align__(16) float was[DA * GG];
    __shared__ __align__(16) float att[SS * GG];
    const int b = blockIdx.x;
    const int t = threadIdx.x;
    for (int i = t; i < DA * GG; i += 256) was[i] = Wa[i];
    __syncthreads();

    if (t < SS) {
        const __hip_bfloat16* xr = xatt + (size_t)(b * SS + t) * DAP;
        float s0 = 0, s1 = 0, s2 = 0, s3 = 0;
        for (int d = 0; d < DA; d += 8) {
            uint4 u = *(const uint4*)(xr + d);
            const float* wp = was + d * 4;
            unsigned uu[4] = {u.x, u.y, u.z, u.w};
#pragma unroll
            for (int j = 0; j < 4; ++j) {
                float fl = __uint_as_float(uu[j] << 16);
                float fh = __uint_as_float(uu[j] & 0xffff0000u);
                const float* w0 = wp + j * 8;
                s0 += fl * w0[0] + fh * w0[4];
                s1 += fl * w0[1] + fh * w0[5];
                s2 += fl * w0[2] + fh * w0[6];
                s3 += fl * w0[3] + fh * w0[7];
            }
        }
        att[t * 4 + 0] = s0; att[t * 4 + 1] = s1;
        att[t * 4 + 2] = s2; att[t * 4 + 3] = s3;
    }
    __syncthreads();
    {
        const int g = t >> 6;      // wave w owns glimpse g
        const int lane = t & 63;
        float mx = -3.0e38f;
        for (int s = lane; s < SS; s += 64) mx = fmaxf(mx, att[s * 4 + g]);
#pragma unroll
        for (int m = 32; m > 0; m >>= 1) mx = fmaxf(mx, __shfl_xor(mx, m));
        float sum = 0.f;
        for (int s = lane; s < SS; s += 64) sum += __expf(att[s * 4 + g] - mx);
#pragma unroll
        for (int m = 32; m > 0; m >>= 1) sum += __shfl_xor(sum, m);
        float inv = __builtin_amdgcn_rcpf(sum);
        for (int s = lane; s < SS; s += 64) att[s * 4 + g] = __expf(att[s * 4 + g] - mx) * inv;
    }
    __syncthreads();
#pragma unroll
    for (int i = 0; i < 4; ++i) {
        int c = 2 * (t + i * 256);
        const __hip_bfloat16* vp = vt + (size_t)b * SS * DV + c;
        float a00 = 0, a01 = 0, a02 = 0, a03 = 0;
        float a10 = 0, a11 = 0, a12 = 0, a13 = 0;
        for (int s = 0; s < SS; ++s) {
            unsigned u = *(const unsigned*)(vp + (size_t)s * DV);
            float v0 = __uint_as_float(u << 16);
            float v1 = __uint_as_float(u & 0xffff0000u);
            float4 aw = *(const float4*)(att + s * 4);
            a00 += v0 * aw.x; a01 += v0 * aw.y; a02 += v0 * aw.z; a03 += v0 * aw.w;
            a10 += v1 * aw.x; a11 += v1 * aw.y; a12 += v1 * aw.z; a13 += v1 * aw.w;
        }
        float* vb = vatt + (size_t)b * GG * DV;
        vb[0 * DV + c] = a00; vb[0 * DV + c + 1] = a10;
        vb[1 * DV + c] = a01; vb[1 * DV + c + 1] = a11;
        vb[2 * DV + c] = a02; vb[2 * DV + c + 1] = a12;
        vb[3 * DV + c] = a03; vb[3 * DV + c + 1] = a13;
    }
}

// ---------------------------------------------------------------------------
extern "C" void kernel_launch(void* const* d_in, const int* in_sizes, int n_in,
                              void* d_out, int out_size, void* d_ws, size_t ws_size,
                              hipStream_t stream) {
    const float* input_v = (const float*)d_in[0];
    const float* x_q     = (const float*)d_in[1];
    const float* Wv      = (const float*)d_in[2];
    const float* bv      = (const float*)d_in[3];
    const float* Wq_att  = (const float*)d_in[4];
    const float* bq_att  = (const float*)d_in[5];
    const float* Wa      = (const float*)d_in[6];
    // d_in[7] = ba: constant over softmax axis -> cancels, unused.
    const float* Wf      = (const float*)d_in[8];
    const float* bf_     = (const float*)d_in[9];
    const float* Wqf     = (const float*)d_in[10];
    const float* bqf     = (const float*)d_in[11];
    const float* Wc      = (const float*)d_in[12];
    const float* bc      = (const float*)d_in[13];
    float* out = (float*)d_out;

    char* wsb = (char*)d_ws;
    size_t off = 0;
    auto carve = [&](size_t bytes) -> void* {
        void* p = wsb + off;
        off += (bytes + 255) & ~(size_t)255;
        return p;
    };
    __hip_bfloat16* vt   = (__hip_bfloat16*)carve((size_t)MROWS * DV * 2);   // 102.8 MB
    __hip_bfloat16* wvt  = (__hip_bfloat16*)carve((size_t)DAP * DV * 2);     //   5.2 MB
    __hip_bfloat16* xatt = (__hip_bfloat16*)carve((size_t)MROWS * DAP * 2);  //  64.2 MB
    float* qatt = (float*)carve((size_t)BB * DAP * 4);
    float* qfus = (float*)carve((size_t)BB * DH * 4);
    float* bvp  = (float*)carve((size_t)DAP * 4);
    float* vatt = (float*)carve((size_t)BB * GG * DV * 4);
    float* xbuf = (float*)carve((size_t)BB * DH * 4);
    (void)ws_size; (void)n_in; (void)in_sizes; (void)out_size;

    pad_bv<<<dim3(5), 256, 0, stream>>>(bv, bvp);
    transpose_v<<<dim3(DV / 64, 4, BB), 256, 0, stream>>>(input_v, vt);
    transpose_w<<<dim3(DAP / 64, DV / 64), 256, 0, stream>>>(Wv, wvt);

    // q branches (fp32): qatt [128][1280] (pad->0), qfus [128][2048]
    gemm_small<1><<<dim3(DAP / 64, 2), 256, 0, stream>>>(
        x_q, DQ, Wq_att, DA, bq_att, qatt, DAP, DAP, DA, DQ, nullptr);
    gemm_small<1><<<dim3(DH / 64, 2), 256, 0, stream>>>(
        x_q, DQ, Wqf, DH, bqf, qfus, DH, DH, DH, DQ, nullptr);

    // big MFMA GEMM -> x_att bf16
    big_gemm<<<dim3(MROWS / 128, DAP / 128), 256, 0, stream>>>(vt, wvt, bvp, qatt, xatt);

    // scores + softmax + glimpse pooling -> v_att fp32 [128][4][2048]
    att_pool<<<dim3(BB), 256, 0, stream>>>(xatt, Wa, vt, vatt);

    // glimpse fusion: xbuf = tanh(tanh(v_att@Wf + bf) * qfus)
    gemm_small<2><<<dim3(DH / 64, 2), 256, 0, stream>>>(
        vatt, GG * DV, Wf, DH / GG, bf_, xbuf, DH, DH, DH, DV, qfus);

    // classifier: out = xbuf @ Wc + bc
    gemm_small<0><<<dim3((NANS + 63) / 64, 2), 256, 0, stream>>>(
        xbuf, DH, Wc, NANS, bc, out, NANS, NANS, NANS, DH, nullptr);
}

// Round 2
// 839.801 us; speedup vs baseline: 2.2569x; 2.2569x over previous
//
#include <hip/hip_runtime.h>
#include <hip/hip_bf16.h>

// Problem constants
#define BB   128
#define DV   2048
#define SS   196
#define DQ   2048
#define DA   1200
#define DAP  1280      // DA padded to 10*128 MFMA n-tiles
#define GG   4
#define DH   2048
#define NANS 3000
#define NANSP 3008     // 47*64
#define MROWS (BB*SS)  // 25088 = 196 * 128 exactly
#define KSPLIT 8
#define KCHUNK (DV/KSPLIT)  // 256

typedef __attribute__((ext_vector_type(8))) short bf16x8;
typedef __attribute__((ext_vector_type(4))) float f32x4;

__device__ __forceinline__ float fast_tanh(float x) {
    float e = __expf(2.0f * x);
    return 1.0f - 2.0f * __builtin_amdgcn_rcpf(e + 1.0f);
}

__device__ __forceinline__ void async_copy16(const void* gsrc, void* ldst) {
    __builtin_amdgcn_global_load_lds(
        (const __attribute__((address_space(1))) void*)gsrc,
        (__attribute__((address_space(3))) void*)ldst, 16, 0, 0);
}

// ---------------------------------------------------------------------------
// zero scores (atomicAdd target)
// ---------------------------------------------------------------------------
__global__ void zero_f32(float* __restrict__ p, int n) {
    int i = blockIdx.x * 256 + threadIdx.x;
    if (i < n) p[i] = 0.f;
}

// pad bv (DA->DAP) and Wa ([DA][4] -> [DAP][4], pad rows 0)
__global__ void pad_misc(const float* __restrict__ bv, const float* __restrict__ Wa,
                         float* __restrict__ bvp, float* __restrict__ wap) {
    int i = blockIdx.x * 256 + threadIdx.x;
    if (i < DAP) bvp[i] = (i < DA) ? bv[i] : 0.f;
    if (i < DAP * GG) {
        int d = i >> 2;
        wap[i] = (d < DA) ? Wa[i] : 0.f;
    }
}

// ---------------------------------------------------------------------------
// K0a: v [B][DV][S] fp32 -> v_t [(b*S+s)][DV] bf16
// ---------------------------------------------------------------------------
__global__ __launch_bounds__(256) void transpose_v(const float* __restrict__ v,
                                                   __hip_bfloat16* __restrict__ vt) {
    __shared__ float tile[64][65];
    const int b  = blockIdx.z;
    const int c0 = blockIdx.x * 64;
    const int s0 = blockIdx.y * 64;
    const int t  = threadIdx.x;
    const int col  = t & 63;
    const int rowb = t >> 6;
    const float* src = v + (size_t)b * DV * SS;
#pragma unroll
    for (int i = 0; i < 16; ++i) {
        int c = rowb + i * 4;
        int s = s0 + col;
        tile[c][col] = (s < SS) ? src[(size_t)(c0 + c) * SS + s] : 0.f;
    }
    __syncthreads();
    const int cpair = (t & 31) * 2;
#pragma unroll
    for (int i = 0; i < 8; ++i) {
        int sl = (t >> 5) + i * 8;
        int s  = s0 + sl;
        if (s < SS) {
            __hip_bfloat162 h2;
            h2.x = __float2bfloat16(tile[cpair][sl]);
            h2.y = __float2bfloat16(tile[cpair + 1][sl]);
            *(__hip_bfloat162*)(vt + ((size_t)b * SS + s) * DV + c0 + cpair) = h2;
        }
    }
}

// ---------------------------------------------------------------------------
// K0b: Wv [DV][DA] fp32 -> wvt [DAP][DV] bf16 (B^T layout), pad rows zeroed
// ---------------------------------------------------------------------------
__global__ __launch_bounds__(256) void transpose_w(const float* __restrict__ Wv,
                                                   __hip_bfloat16* __restrict__ wvt) {
    __shared__ float tile[64][65];
    const int d0 = blockIdx.x * 64;
    const int c0 = blockIdx.y * 64;
    const int t  = threadIdx.x;
    const int col  = t & 63;
    const int rowb = t >> 6;
#pragma unroll
    for (int i = 0; i < 16; ++i) {
        int c = rowb + i * 4;
        int d = d0 + col;
        tile[c][col] = (d < DA) ? Wv[(size_t)(c0 + c) * DA + d] : 0.f;
    }
    __syncthreads();
#pragma unroll
    for (int i = 0; i < 16; ++i) {
        int dl = rowb + i * 4;
        wvt[(size_t)(d0 + dl) * DV + c0 + col] = __float2bfloat16(tile[col][dl]);
    }
}

// ---------------------------------------------------------------------------
// Split-K fp32 partial GEMM: Cp[ks][128][Npad] = A[128,kchunk] * B[kchunk,64tile]
// grid (ntiles, KSPLIT), 256 thr. Thread tile 4m x 8n. A^T in LDS (stride 132).
// FUS=1: fusion addressing (A=vatt strided by glimpse, B=Wf[g]).
// ---------------------------------------------------------------------------
template <int FUS>
__global__ __launch_bounds__(256) void gemm_partial(
    const float* __restrict__ A, int lda,
    const float* __restrict__ Bm, int ldb,
    float* __restrict__ Cp, int Npad, int Nreal) {
    __shared__ float As[64 * 132];   // As[kk][m], stride 132 (16B-aligned rows)
    __shared__ float Bs[64 * 68];    // Bs[kk][n]
    const int t     = threadIdx.x;
    const int n0    = blockIdx.x * 64;
    const int kbase = blockIdx.y * KCHUNK;

    const float* Aeff = A;
    const float* Beff = Bm;
    int ncol0 = n0;
    if (FUS) {
        int g = n0 >> 9;
        Aeff  = A + g * 2048;
        Beff  = Bm + (size_t)g * 2048 * 512;
        ncol0 = n0 & 511;
    }

    const int tm = (t & 31) * 4;
    const int tn = (t >> 5) * 8;
    float acc[4][8] = {};

    for (int k0 = kbase; k0 < kbase + KCHUNK; k0 += 64) {
        {
            int kk = t & 63, mb = (t >> 6) * 32;
#pragma unroll
            for (int i = 0; i < 32; ++i)
                As[kk * 132 + mb + i] = Aeff[(size_t)(mb + i) * lda + k0 + kk];
        }
        {
            int j = t & 63, kr = t >> 6;
            bool ok = (n0 + j) < Nreal;
#pragma unroll
            for (int i = 0; i < 16; ++i) {
                int k = kr + i * 4;
                Bs[k * 68 + j] = ok ? Beff[(size_t)(k0 + k) * ldb + ncol0 + j] : 0.f;
            }
        }
        __syncthreads();
#pragma unroll
        for (int kk = 0; kk < 64; ++kk) {
            const float4 av = *(const float4*)(As + kk * 132 + tm);
            const float4 b0 = *(const float4*)(Bs + kk * 68 + tn);
            const float4 b1 = *(const float4*)(Bs + kk * 68 + tn + 4);
            const float am[4] = {av.x, av.y, av.z, av.w};
#pragma unroll
            for (int i = 0; i < 4; ++i) {
                acc[i][0] += am[i] * b0.x; acc[i][1] += am[i] * b0.y;
                acc[i][2] += am[i] * b0.z; acc[i][3] += am[i] * b0.w;
                acc[i][4] += am[i] * b1.x; acc[i][5] += am[i] * b1.y;
                acc[i][6] += am[i] * b1.z; acc[i][7] += am[i] * b1.w;
            }
        }
        __syncthreads();
    }
#pragma unroll
    for (int i = 0; i < 4; ++i) {
        size_t base = ((size_t)blockIdx.y * 128 + tm + i) * Npad + n0 + tn;
        float4 v0 = {acc[i][0], acc[i][1], acc[i][2], acc[i][3]};
        float4 v1 = {acc[i][4], acc[i][5], acc[i][6], acc[i][7]};
        *(float4*)(Cp + base) = v0;
        *(float4*)(Cp + base + 4) = v1;
    }
}

// ---------------------------------------------------------------------------
// Epilogue: sum 8 partials, apply mode, write.
// MODE 0: +bias (classifier) | MODE 1: tanh(+bias), pad->0 | MODE 2: MLB fusion
// grid (ceil(Npad/256), 128)
// ---------------------------------------------------------------------------
template <int MODE>
__global__ __launch_bounds__(256) void gemm_epilogue(
    const float* __restrict__ Cp, int Npad, int Nreal,
    const float* __restrict__ bias, const float* __restrict__ aux,
    float* __restrict__ out, int ldo) {
    int n = blockIdx.x * 256 + threadIdx.x;
    int m = blockIdx.y;
    if (n >= Npad) return;
    float s = 0.f;
#pragma unroll
    for (int ks = 0; ks < KSPLIT; ++ks)
        s += Cp[((size_t)ks * 128 + m) * Npad + n];
    float o;
    if (MODE == 0) {
        if (n >= Nreal) return;
        o = s + bias[n];
    } else if (MODE == 1) {
        o = (n < Nreal) ? fast_tanh(s + bias[n]) : 0.f;
    } else {
        float xv = fast_tanh(s + bias[n]);
        o = fast_tanh(xv * aux[(size_t)m * 2048 + n]);
    }
    out[(size_t)m * ldo + n] = o;
}

// ---------------------------------------------------------------------------
// K1: big MFMA GEMM (m97 structure) with FUSED score reduction.
// xv = tanh(vt@wvt^T + bv); xa = tanh(xv * qatt); scores[r][g] += xa * Wa[d][g]
// No xatt materialization. Scores via shuffle-reduce + atomicAdd.
// ---------------------------------------------------------------------------
__global__ __launch_bounds__(256) void big_gemm(
    const __hip_bfloat16* __restrict__ vt,
    const __hip_bfloat16* __restrict__ wt,
    const float* __restrict__ bvp,
    const float* __restrict__ qatt,
    const float* __restrict__ wap,
    float* __restrict__ scores) {
    __shared__ __hip_bfloat16 As[128 * 32];
    __shared__ __hip_bfloat16 Bs[128 * 32];
    __shared__ float wa_s[128 * 4];
    const int t    = threadIdx.x;
    const int lane = t & 63;
    const int w    = t >> 6;
    const int wm   = w >> 1, wn = w & 1;
    const int m0   = blockIdx.x * 128;
    const int n0   = blockIdx.y * 128;

    if (t < 128) *(float4*)(wa_s + t * 4) = *(const float4*)(wap + (n0 + t) * 4);

    f32x4 acc[4][4];
#pragma unroll
    for (int i = 0; i < 4; ++i)
#pragma unroll
        for (int j = 0; j < 4; ++j) acc[i][j] = (f32x4){0.f, 0.f, 0.f, 0.f};

    const int lrow = lane >> 2;
    const int lcol = (lane & 3) * 8;

    for (int k0 = 0; k0 < DV; k0 += 32) {
        __syncthreads();
#pragma unroll
        for (int i = 0; i < 2; ++i) {
            int r = w * 32 + i * 16;
            async_copy16(vt + (size_t)(m0 + r + lrow) * DV + k0 + lcol, (void*)(As + r * 32));
            async_copy16(wt + (size_t)(n0 + r + lrow) * DV + k0 + lcol, (void*)(Bs + r * 32));
        }
        __syncthreads();
        bf16x8 a[4], b[4];
        const int ko = (lane >> 4) * 8;
        const int ra = (wm * 64 + (lane & 15)) * 32 + ko;
        const int rb = (wn * 64 + (lane & 15)) * 32 + ko;
#pragma unroll
        for (int mi = 0; mi < 4; ++mi) a[mi] = *(const bf16x8*)(As + ra + mi * 16 * 32);
#pragma unroll
        for (int ni = 0; ni < 4; ++ni) b[ni] = *(const bf16x8*)(Bs + rb + ni * 16 * 32);
#pragma unroll
        for (int mi = 0; mi < 4; ++mi)
#pragma unroll
            for (int ni = 0; ni < 4; ++ni)
                acc[mi][ni] = __builtin_amdgcn_mfma_f32_16x16x32_bf16(a[mi], b[ni], acc[mi][ni], 0, 0, 0);
    }

    // Epilogue: C/D layout col=lane&15, row=(lane>>4)*4+reg
    const int colb_l = wn * 64 + (lane & 15);      // col within 128-tile
    const int colb_g = n0 + colb_l;                // global col
    float bvv[4];
    float4 wv[4];
#pragma unroll
    for (int ni = 0; ni < 4; ++ni) {
        bvv[ni] = bvp[colb_g + ni * 16];
        wv[ni]  = *(const float4*)(wa_s + (colb_l + ni * 16) * 4);
    }
#pragma unroll
    for (int mi = 0; mi < 4; ++mi) {
#pragma unroll
        for (int r = 0; r < 4; ++r) {
            int row = m0 + wm * 64 + mi * 16 + ((lane >> 4) << 2) + r;
            unsigned bb = (unsigned)row / 196u;
            const float* qrow = qatt + (size_t)bb * DAP;
            float p0 = 0.f, p1 = 0.f, p2 = 0.f, p3 = 0.f;
#pragma unroll
            for (int ni = 0; ni < 4; ++ni) {
                float xv = fast_tanh(acc[mi][ni][r] + bvv[ni]);
                float xa = fast_tanh(xv * qrow[colb_g + ni * 16]);
                p0 += xa * wv[ni].x; p1 += xa * wv[ni].y;
                p2 += xa * wv[ni].z; p3 += xa * wv[ni].w;
            }
#pragma unroll
            for (int mk = 1; mk < 16; mk <<= 1) {
                p0 += __shfl_xor(p0, mk); p1 += __shfl_xor(p1, mk);
                p2 += __shfl_xor(p2, mk); p3 += __shfl_xor(p3, mk);
            }
            if ((lane & 15) == 0) {
                float* sp = scores + (size_t)row * 4;
                atomicAdd(sp + 0, p0); atomicAdd(sp + 1, p1);
                atomicAdd(sp + 2, p2); atomicAdd(sp + 3, p3);
            }
        }
    }
}

// ---------------------------------------------------------------------------
// K2: softmax over s (per b,g) + glimpse pooling over a 512-channel chunk.
// grid (4 cchunks, 128 b), 256 threads. Softmax recomputed per chunk (cheap).
// ---------------------------------------------------------------------------
__global__ __launch_bounds__(256) void softmax_pool(
    const float* __restrict__ scores,
    const __hip_bfloat16* __restrict__ vt,
    float* __restrict__ vatt) {
    __shared__ __align__(16) float att[SS * GG];
    const int b = blockIdx.y;
    const int t = threadIdx.x;
    if (t < SS) *(float4*)(att + t * 4) = *(const float4*)(scores + ((size_t)b * SS + t) * 4);
    __syncthreads();
    {
        const int g = t >> 6;
        const int lane = t & 63;
        float mx = -3.0e38f;
        for (int s = lane; s < SS; s += 64) mx = fmaxf(mx, att[s * 4 + g]);
#pragma unroll
        for (int m = 32; m > 0; m >>= 1) mx = fmaxf(mx, __shfl_xor(mx, m));
        float sum = 0.f;
        for (int s = lane; s < SS; s += 64) sum += __expf(att[s * 4 + g] - mx);
#pragma unroll
        for (int m = 32; m > 0; m >>= 1) sum += __shfl_xor(sum, m);
        float inv = __builtin_amdgcn_rcpf(sum);
        for (int s = lane; s < SS; s += 64) att[s * 4 + g] = __expf(att[s * 4 + g] - mx) * inv;
    }
    __syncthreads();
    const int c = blockIdx.x * 512 + t * 2;
    const __hip_bfloat16* vp = vt + (size_t)b * SS * DV + c;
    float a00 = 0, a01 = 0, a02 = 0, a03 = 0;
    float a10 = 0, a11 = 0, a12 = 0, a13 = 0;
#pragma unroll 4
    for (int s = 0; s < SS; ++s) {
        unsigned u = *(const unsigned*)(vp + (size_t)s * DV);
        float v0 = __uint_as_float(u << 16);
        float v1 = __uint_as_float(u & 0xffff0000u);
        float4 aw = *(const float4*)(att + s * 4);
        a00 += v0 * aw.x; a01 += v0 * aw.y; a02 += v0 * aw.z; a03 += v0 * aw.w;
        a10 += v1 * aw.x; a11 += v1 * aw.y; a12 += v1 * aw.z; a13 += v1 * aw.w;
    }
    float* vb = vatt + (size_t)b * GG * DV;
    vb[0 * DV + c] = a00; vb[0 * DV + c + 1] = a10;
    vb[1 * DV + c] = a01; vb[1 * DV + c + 1] = a11;
    vb[2 * DV + c] = a02; vb[2 * DV + c + 1] = a12;
    vb[3 * DV + c] = a03; vb[3 * DV + c + 1] = a13;
}

// ---------------------------------------------------------------------------
extern "C" void kernel_launch(void* const* d_in, const int* in_sizes, int n_in,
                              void* d_out, int out_size, void* d_ws, size_t ws_size,
                              hipStream_t stream) {
    const float* input_v = (const float*)d_in[0];
    const float* x_q     = (const float*)d_in[1];
    const float* Wv      = (const float*)d_in[2];
    const float* bv      = (const float*)d_in[3];
    const float* Wq_att  = (const float*)d_in[4];
    const float* bq_att  = (const float*)d_in[5];
    const float* Wa      = (const float*)d_in[6];
    // d_in[7] = ba: constant over softmax axis -> cancels, unused.
    const float* Wf      = (const float*)d_in[8];
    const float* bf_     = (const float*)d_in[9];
    const float* Wqf     = (const float*)d_in[10];
    const float* bqf     = (const float*)d_in[11];
    const float* Wc      = (const float*)d_in[12];
    const float* bc      = (const float*)d_in[13];
    float* out = (float*)d_out;

    char* wsb = (char*)d_ws;
    size_t off = 0;
    auto carve = [&](size_t bytes) -> void* {
        void* p = wsb + off;
        off += (bytes + 255) & ~(size_t)255;
        return p;
    };
    __hip_bfloat16* vt  = (__hip_bfloat16*)carve((size_t)MROWS * DV * 2);       // 102.8 MB
    __hip_bfloat16* wvt = (__hip_bfloat16*)carve((size_t)DAP * DV * 2);         //   5.2 MB
    float* Cp     = (float*)carve((size_t)KSPLIT * 128 * NANSP * 4);            //  12.3 MB
    float* scores = (float*)carve((size_t)MROWS * GG * 4);                      //   0.4 MB
    float* qatt   = (float*)carve((size_t)BB * DAP * 4);
    float* qfus   = (float*)carve((size_t)BB * DH * 4);
    float* bvp    = (float*)carve((size_t)DAP * 4);
    float* wap    = (float*)carve((size_t)DAP * GG * 4);
    float* vatt   = (float*)carve((size_t)BB * GG * DV * 4);
    float* xbuf   = (float*)carve((size_t)BB * DH * 4);
    (void)ws_size; (void)n_in; (void)in_sizes; (void)out_size;

    zero_f32<<<dim3((MROWS * GG + 255) / 256), 256, 0, stream>>>(scores, MROWS * GG);
    pad_misc<<<dim3(20), 256, 0, stream>>>(bv, Wa, bvp, wap);
    transpose_v<<<dim3(DV / 64, 4, BB), 256, 0, stream>>>(input_v, vt);
    transpose_w<<<dim3(DAP / 64, DV / 64), 256, 0, stream>>>(Wv, wvt);

    // q-branch GEMMs (split-K fp32)
    gemm_partial<0><<<dim3(DAP / 64, KSPLIT), 256, 0, stream>>>(x_q, DQ, Wq_att, DA, Cp, DAP, DA);
    gemm_epilogue<1><<<dim3(DAP / 256, BB), 256, 0, stream>>>(Cp, DAP, DA, bq_att, nullptr, qatt, DAP);
    gemm_partial<0><<<dim3(DH / 64, KSPLIT), 256, 0, stream>>>(x_q, DQ, Wqf, DH, Cp, DH, DH);
    gemm_epilogue<1><<<dim3(DH / 256, BB), 256, 0, stream>>>(Cp, DH, DH, bqf, nullptr, qfus, DH);

    // big MFMA GEMM with fused score reduction -> scores
    big_gemm<<<dim3(MROWS / 128, DAP / 128), 256, 0, stream>>>(vt, wvt, bvp, qatt, wap, scores);

    // softmax over spatial + glimpse pooling -> vatt [128][4][2048]
    softmax_pool<<<dim3(4, BB), 256, 0, stream>>>(scores, vt, vatt);

    // glimpse fusion: xbuf = tanh(tanh(vatt@Wf + bf) * qfus)
    gemm_partial<1><<<dim3(DH / 64, KSPLIT), 256, 0, stream>>>(vatt, GG * DV, Wf, DH / GG, Cp, DH, DH);
    gemm_epilogue<2><<<dim3(DH / 256, BB), 256, 0, stream>>>(Cp, DH, DH, bf_, qfus, xbuf, DH);

    // classifier: out = xbuf @ Wc + bc
    gemm_partial<0><<<dim3(NANSP / 64, KSPLIT), 256, 0, stream>>>(xbuf, DH, Wc, NANS, Cp, NANSP, NANS);
    gemm_epilogue<0><<<dim3(NANSP / 256 + 1, BB), 256, 0, stream>>>(Cp, NANSP, NANS, bc, nullptr, out, NANS);
}

// Round 3
// 777.257 us; speedup vs baseline: 2.4385x; 1.0805x over previous
//
#include <hip/hip_runtime.h>
#include <hip/hip_bf16.h>

// Problem constants
#define BB   128
#define DV   2048
#define SS   196
#define DQ   2048
#define DA   1200
#define DAP  1280      // DA padded to 10*128 MFMA n-tiles
#define GG   4
#define DH   2048
#define NANS 3000
#define NANSP 3008     // 47*64
#define MROWS (BB*SS)  // 25088 = 196 * 128 exactly
#define NT   10        // n-tiles in big GEMM
#define KSPLIT 8
#define KCHUNK (DV/KSPLIT)  // 256
#define NQ   (DAP + DH)     // 3328 merged q-branch cols

typedef __attribute__((ext_vector_type(8))) short bf16x8;
typedef __attribute__((ext_vector_type(4))) float f32x4;

__device__ __forceinline__ float fast_tanh(float x) {
    float e = __expf(2.0f * x);
    return 1.0f - 2.0f * __builtin_amdgcn_rcpf(e + 1.0f);
}

__device__ __forceinline__ void async_copy16(const void* gsrc, void* ldst) {
    __builtin_amdgcn_global_load_lds(
        (const __attribute__((address_space(1))) void*)gsrc,
        (__attribute__((address_space(3))) void*)ldst, 16, 0, 0);
}

// pad bv (DA->DAP) and Wa ([DA][4] -> [DAP][4], pad rows 0)
__global__ void pad_misc(const float* __restrict__ bv, const float* __restrict__ Wa,
                         float* __restrict__ bvp, float* __restrict__ wap) {
    int i = blockIdx.x * 256 + threadIdx.x;
    if (i < DAP) bvp[i] = (i < DA) ? bv[i] : 0.f;
    if (i < DAP * GG) {
        int d = i >> 2;
        wap[i] = (d < DA) ? Wa[i] : 0.f;
    }
}

// ---------------------------------------------------------------------------
// K0a: v [B][DV][S] fp32 -> v_t [(b*S+s)][DV] bf16. 128c x 64s tiles; stores
// are full-wave 256B coalesced (64 lanes x bf16x2 over 128 channels).
// ---------------------------------------------------------------------------
__global__ __launch_bounds__(256) void transpose_v(const float* __restrict__ v,
                                                   __hip_bfloat16* __restrict__ vt) {
    __shared__ float tile[128][65];
    const int b  = blockIdx.z;
    const int c0 = blockIdx.x * 128;
    const int s0 = blockIdx.y * 64;
    const int t  = threadIdx.x;
    const int sl = t & 63;
    const int cr = t >> 6;
    const float* src = v + (size_t)b * DV * SS;
    const int sg = s0 + sl;
    const bool sok = sg < SS;
#pragma unroll
    for (int i = 0; i < 32; ++i) {
        int c = cr + i * 4;
        tile[c][sl] = sok ? src[(size_t)(c0 + c) * SS + sg] : 0.f;
    }
    __syncthreads();
    const int cp = (t & 63) * 2;
#pragma unroll
    for (int i = 0; i < 16; ++i) {
        int s = (t >> 6) + i * 4;
        int sgl = s0 + s;
        if (sgl < SS) {
            __hip_bfloat162 h2;
            h2.x = __float2bfloat16(tile[cp][s]);
            h2.y = __float2bfloat16(tile[cp + 1][s]);
            *(__hip_bfloat162*)(vt + ((size_t)b * SS + sgl) * DV + c0 + cp) = h2;
        }
    }
}

// ---------------------------------------------------------------------------
// K0b: Wv [DV][DA] fp32 -> wvt [DAP][DV] bf16 (B^T layout), pad rows zeroed
// ---------------------------------------------------------------------------
__global__ __launch_bounds__(256) void transpose_w(const float* __restrict__ Wv,
                                                   __hip_bfloat16* __restrict__ wvt) {
    __shared__ float tile[64][65];
    const int d0 = blockIdx.x * 64;
    const int c0 = blockIdx.y * 64;
    const int t  = threadIdx.x;
    const int col  = t & 63;
    const int rowb = t >> 6;
#pragma unroll
    for (int i = 0; i < 16; ++i) {
        int c = rowb + i * 4;
        int d = d0 + col;
        tile[c][col] = (d < DA) ? Wv[(size_t)(c0 + c) * DA + d] : 0.f;
    }
    __syncthreads();
#pragma unroll
    for (int i = 0; i < 16; ++i) {
        int dl = rowb + i * 4;
        wvt[(size_t)(d0 + dl) * DV + c0 + col] = __float2bfloat16(tile[col][dl]);
    }
}

// ---------------------------------------------------------------------------
// Split-K fp32 partial GEMM: Cp[ks][128][Npad] = A[128,kchunk] * B[kchunk,64tile]
// grid (ntiles, KSPLIT). SEL 0: classifier | SEL 1: glimpse fusion | SEL 2:
// merged q-branch (cols [0,DAP) -> Wq_att, cols [DAP,NQ) -> Wqf).
// ---------------------------------------------------------------------------
template <int SEL>
__global__ __launch_bounds__(256) void gemm_partial(
    const float* __restrict__ A, int lda,
    const float* __restrict__ Bm, const float* __restrict__ B2,
    float* __restrict__ Cp, int Npad) {
    __shared__ float As[64 * 132];   // As[kk][m]
    __shared__ float Bs[64 * 68];    // Bs[kk][n]
    const int t     = threadIdx.x;
    const int n0    = blockIdx.x * 64;
    const int kbase = blockIdx.y * KCHUNK;

    const float* Aeff = A;
    const float* Beff;
    int ldb, ncol0, nlim;
    if (SEL == 0) {            // classifier: B=Wc [2048][3000]
        Beff = Bm; ldb = NANS; ncol0 = n0; nlim = NANS;
    } else if (SEL == 1) {     // fusion: A=vatt per glimpse, B=Wf[g] [2048][512]
        int gg = n0 >> 9;
        Aeff = A + gg * 2048;
        Beff = Bm + (size_t)gg * 2048 * 512;
        ldb = 512; ncol0 = n0 & 511; nlim = 1 << 30;
    } else {                   // merged q-branch
        if (n0 < DAP) { Beff = Bm; ldb = DA; ncol0 = n0;      nlim = DA; }
        else          { Beff = B2; ldb = DH; ncol0 = n0 - DAP; nlim = 1 << 30; }
    }

    const int tm = (t & 31) * 4;
    const int tn = (t >> 5) * 8;
    float acc[4][8] = {};

    for (int k0 = kbase; k0 < kbase + KCHUNK; k0 += 64) {
        {
            int kk = t & 63, mb = (t >> 6) * 32;
#pragma unroll
            for (int i = 0; i < 32; ++i)
                As[kk * 132 + mb + i] = Aeff[(size_t)(mb + i) * lda + k0 + kk];
        }
        {
            int j = t & 63, kr = t >> 6;
            bool ok = (ncol0 + j) < nlim;
#pragma unroll
            for (int i = 0; i < 16; ++i) {
                int k = kr + i * 4;
                Bs[k * 68 + j] = ok ? Beff[(size_t)(k0 + k) * ldb + ncol0 + j] : 0.f;
            }
        }
        __syncthreads();
#pragma unroll
        for (int kk = 0; kk < 64; ++kk) {
            const float4 av = *(const float4*)(As + kk * 132 + tm);
            const float4 b0 = *(const float4*)(Bs + kk * 68 + tn);
            const float4 b1 = *(const float4*)(Bs + kk * 68 + tn + 4);
            const float am[4] = {av.x, av.y, av.z, av.w};
#pragma unroll
            for (int i = 0; i < 4; ++i) {
                acc[i][0] += am[i] * b0.x; acc[i][1] += am[i] * b0.y;
                acc[i][2] += am[i] * b0.z; acc[i][3] += am[i] * b0.w;
                acc[i][4] += am[i] * b1.x; acc[i][5] += am[i] * b1.y;
                acc[i][6] += am[i] * b1.z; acc[i][7] += am[i] * b1.w;
            }
        }
        __syncthreads();
    }
#pragma unroll
    for (int i = 0; i < 4; ++i) {
        size_t base = ((size_t)blockIdx.y * 128 + tm + i) * Npad + n0 + tn;
        float4 v0 = {acc[i][0], acc[i][1], acc[i][2], acc[i][3]};
        float4 v1 = {acc[i][4], acc[i][5], acc[i][6], acc[i][7]};
        *(float4*)(Cp + base) = v0;
        *(float4*)(Cp + base + 4) = v1;
    }
}

// Generic epilogue: MODE 0: +bias (classifier) | MODE 2: MLB glimpse fusion
template <int MODE>
__global__ __launch_bounds__(256) void gemm_epilogue(
    const float* __restrict__ Cp, int Npad, int Nreal,
    const float* __restrict__ bias, const float* __restrict__ aux,
    float* __restrict__ out, int ldo) {
    int n = blockIdx.x * 256 + threadIdx.x;
    int m = blockIdx.y;
    if (n >= Npad) return;
    float s = 0.f;
#pragma unroll
    for (int ks = 0; ks < KSPLIT; ++ks)
        s += Cp[((size_t)ks * 128 + m) * Npad + n];
    if (MODE == 0) {
        if (n >= Nreal) return;
        out[(size_t)m * ldo + n] = s + bias[n];
    } else {
        float xv = fast_tanh(s + bias[n]);
        out[(size_t)m * ldo + n] = fast_tanh(xv * aux[(size_t)m * 2048 + n]);
    }
}

// q-branch epilogue: cols [0,DAP) -> qatt (tanh, pad->0), [DAP,NQ) -> qfus
__global__ __launch_bounds__(256) void epilogue_q(
    const float* __restrict__ Cp,
    const float* __restrict__ bqa, const float* __restrict__ bqf,
    float* __restrict__ qatt, float* __restrict__ qfus) {
    int n = blockIdx.x * 256 + threadIdx.x;
    int m = blockIdx.y;
    if (n >= NQ) return;
    float s = 0.f;
#pragma unroll
    for (int ks = 0; ks < KSPLIT; ++ks)
        s += Cp[((size_t)ks * 128 + m) * NQ + n];
    if (n < DAP) {
        qatt[(size_t)m * DAP + n] = (n < DA) ? fast_tanh(s + bqa[n]) : 0.f;
    } else {
        int j = n - DAP;
        qfus[(size_t)m * DH + j] = fast_tanh(s + bqf[j]);
    }
}

// ---------------------------------------------------------------------------
// K1: big MFMA GEMM, BK=64, XOR-swizzled LDS, grid swizzled for A L2-reuse.
// xv = tanh(vt@wvt^T + bv); xa = tanh(xv * qatt); score partials per n-tile
// accumulated in LDS -> scores_p[nt][row][4] (no atomics, deterministic).
// Grid 1D 1960: groups of 80 = 8 m-tiles x 10 n-tiles; bid%8 tracks XCD so
// each XCD reuses one A-tile from its own L2 across all 10 n-tiles.
// ---------------------------------------------------------------------------
__global__ __launch_bounds__(256) void big_gemm(
    const __hip_bfloat16* __restrict__ vt,
    const __hip_bfloat16* __restrict__ wt,
    const float* __restrict__ bvp,
    const float* __restrict__ qatt,
    const float* __restrict__ wap,
    float* __restrict__ scores_p) {
    __shared__ __hip_bfloat16 As[128 * 64];
    __shared__ __hip_bfloat16 Bs[128 * 64];
    __shared__ float wa_s[128 * 4];
    __shared__ float sc[128 * 4];
    __shared__ float qs[2 * 128];
    const int t    = threadIdx.x;
    const int lane = t & 63;
    const int w    = t >> 6;
    const int wm   = w >> 1, wn = w & 1;

    int bid = blockIdx.x;
    int grp = bid / 80, r = bid % 80;
    int mt, nt;
    if (grp < 24) { mt = grp * 8 + (r & 7); nt = r >> 3; }
    else          { mt = 192 + (r & 3);     nt = r >> 2; }   // tail: 4m x 10n
    const int m0 = mt * 128, n0 = nt * 128;
    const int b0 = m0 / SS;
    const int b1 = (m0 + 127) / SS;
    const int bsplit = (b0 + 1) * SS;

    if (t < 128) {
        *(float4*)(wa_s + t * 4) = *(const float4*)(wap + (n0 + t) * 4);
        *(float4*)(sc + t * 4) = (float4){0.f, 0.f, 0.f, 0.f};
        qs[t]       = qatt[(size_t)b0 * DAP + n0 + t];
        qs[128 + t] = qatt[(size_t)b1 * DAP + n0 + t];
    }

    f32x4 acc[4][4];
#pragma unroll
    for (int i = 0; i < 4; ++i)
#pragma unroll
        for (int j = 0; j < 4; ++j) acc[i][j] = (f32x4){0.f, 0.f, 0.f, 0.f};

    // Staging: lane i -> LDS row (i>>3 within 8-row group), chunk (i&7).
    // Source chunk = (i&7) ^ (i>>3)  => stored chunk p of row R holds
    // global chunk p ^ (R&7)  (conflict-free b128 reads at 128B row stride).
    const int srow   = lane >> 3;
    const int schunk = (lane & 7) ^ srow;
    const __hip_bfloat16* aG = vt + (size_t)(m0 + w * 32 + srow) * DV + schunk * 8;
    const __hip_bfloat16* bG = wt + (size_t)(n0 + w * 32 + srow) * DV + schunk * 8;
    __hip_bfloat16* aL = As + (w * 32) * 64;
    __hip_bfloat16* bL = Bs + (w * 32) * 64;

    for (int k0 = 0; k0 < DV; k0 += 64) {
        __syncthreads();
#pragma unroll
        for (int j = 0; j < 4; ++j) {
            async_copy16(aG + (size_t)(j * 8) * DV + k0, aL + j * 8 * 64);
            async_copy16(bG + (size_t)(j * 8) * DV + k0, bL + j * 8 * 64);
        }
        __syncthreads();
#pragma unroll
        for (int ks = 0; ks < 2; ++ks) {
            const int cx = ((ks * 4 + (lane >> 4)) ^ (lane & 7)) * 8;
            bf16x8 a[4], b[4];
#pragma unroll
            for (int mi = 0; mi < 4; ++mi)
                a[mi] = *(const bf16x8*)(As + (wm * 64 + mi * 16 + (lane & 15)) * 64 + cx);
#pragma unroll
            for (int ni = 0; ni < 4; ++ni)
                b[ni] = *(const bf16x8*)(Bs + (wn * 64 + ni * 16 + (lane & 15)) * 64 + cx);
#pragma unroll
            for (int mi = 0; mi < 4; ++mi)
#pragma unroll
                for (int ni = 0; ni < 4; ++ni)
                    acc[mi][ni] = __builtin_amdgcn_mfma_f32_16x16x32_bf16(a[mi], b[ni], acc[mi][ni], 0, 0, 0);
        }
    }

    // Epilogue: C/D layout col=lane&15, row=(lane>>4)*4+reg  [m89/m91]
    const int colb_l = wn * 64 + (lane & 15);
    const int colb_g = n0 + colb_l;
    float bvv[4];
    float4 wv[4];
#pragma unroll
    for (int ni = 0; ni < 4; ++ni) {
        bvv[ni] = bvp[colb_g + ni * 16];
        wv[ni]  = *(const float4*)(wa_s + (colb_l + ni * 16) * 4);
    }
#pragma unroll
    for (int mi = 0; mi < 4; ++mi) {
#pragma unroll
        for (int rr = 0; rr < 4; ++rr) {
            int lrow = wm * 64 + mi * 16 + ((lane >> 4) << 2) + rr;   // 0..127
            int row  = m0 + lrow;
            int qoff = (row >= bsplit) ? 128 : 0;
            float p0 = 0.f, p1 = 0.f, p2 = 0.f, p3 = 0.f;
#pragma unroll
            for (int ni = 0; ni < 4; ++ni) {
                float xv = fast_tanh(acc[mi][ni][rr] + bvv[ni]);
                float xa = fast_tanh(xv * qs[qoff + colb_l + ni * 16]);
                p0 += xa * wv[ni].x; p1 += xa * wv[ni].y;
                p2 += xa * wv[ni].z; p3 += xa * wv[ni].w;
            }
#pragma unroll
            for (int mk = 1; mk < 16; mk <<= 1) {
                p0 += __shfl_xor(p0, mk); p1 += __shfl_xor(p1, mk);
                p2 += __shfl_xor(p2, mk); p3 += __shfl_xor(p3, mk);
            }
            if ((lane & 15) == 0) {
                atomicAdd(sc + lrow * 4 + 0, p0);
                atomicAdd(sc + lrow * 4 + 1, p1);
                atomicAdd(sc + lrow * 4 + 2, p2);
                atomicAdd(sc + lrow * 4 + 3, p3);
            }
        }
    }
    __syncthreads();
    if (t < 128)
        *(float4*)(scores_p + ((size_t)nt * MROWS + m0 + t) * 4) = *(float4*)(sc + t * 4);
}

// ---------------------------------------------------------------------------
// K2: sum score partials -> softmax over s -> glimpse pooling (512-ch chunk).
// ---------------------------------------------------------------------------
__global__ __launch_bounds__(256) void softmax_pool(
    const float* __restrict__ scores_p,
    const __hip_bfloat16* __restrict__ vt,
    float* __restrict__ vatt) {
    __shared__ __align__(16) float att[SS * GG];
    const int b = blockIdx.y;
    const int t = threadIdx.x;
    if (t < SS) {
        float4 s = {0.f, 0.f, 0.f, 0.f};
#pragma unroll
        for (int ntile = 0; ntile < NT; ++ntile) {
            float4 p = *(const float4*)(scores_p + ((size_t)ntile * MROWS + b * SS + t) * 4);
            s.x += p.x; s.y += p.y; s.z += p.z; s.w += p.w;
        }
        *(float4*)(att + t * 4) = s;
    }
    __syncthreads();
    {
        const int g = t >> 6;
        const int lane = t & 63;
        float mx = -3.0e38f;
        for (int s = lane; s < SS; s += 64) mx = fmaxf(mx, att[s * 4 + g]);
#pragma unroll
        for (int m = 32; m > 0; m >>= 1) mx = fmaxf(mx, __shfl_xor(mx, m));
        float sum = 0.f;
        for (int s = lane; s < SS; s += 64) sum += __expf(att[s * 4 + g] - mx);
#pragma unroll
        for (int m = 32; m > 0; m >>= 1) sum += __shfl_xor(sum, m);
        float inv = __builtin_amdgcn_rcpf(sum);
        for (int s = lane; s < SS; s += 64) att[s * 4 + g] = __expf(att[s * 4 + g] - mx) * inv;
    }
    __syncthreads();
    const int c = blockIdx.x * 512 + t * 2;
    const __hip_bfloat16* vp = vt + (size_t)b * SS * DV + c;
    float a00 = 0, a01 = 0, a02 = 0, a03 = 0;
    float a10 = 0, a11 = 0, a12 = 0, a13 = 0;
#pragma unroll 4
    for (int s = 0; s < SS; ++s) {
        unsigned u = *(const unsigned*)(vp + (size_t)s * DV);
        float v0 = __uint_as_float(u << 16);
        float v1 = __uint_as_float(u & 0xffff0000u);
        float4 aw = *(const float4*)(att + s * 4);
        a00 += v0 * aw.x; a01 += v0 * aw.y; a02 += v0 * aw.z; a03 += v0 * aw.w;
        a10 += v1 * aw.x; a11 += v1 * aw.y; a12 += v1 * aw.z; a13 += v1 * aw.w;
    }
    float* vb = vatt + (size_t)b * GG * DV;
    vb[0 * DV + c] = a00; vb[0 * DV + c + 1] = a10;
    vb[1 * DV + c] = a01; vb[1 * DV + c + 1] = a11;
    vb[2 * DV + c] = a02; vb[2 * DV + c + 1] = a12;
    vb[3 * DV + c] = a03; vb[3 * DV + c + 1] = a13;
}

// ---------------------------------------------------------------------------
extern "C" void kernel_launch(void* const* d_in, const int* in_sizes, int n_in,
                              void* d_out, int out_size, void* d_ws, size_t ws_size,
                              hipStream_t stream) {
    const float* input_v = (const float*)d_in[0];
    const float* x_q     = (const float*)d_in[1];
    const float* Wv      = (const float*)d_in[2];
    const float* bv      = (const float*)d_in[3];
    const float* Wq_att  = (const float*)d_in[4];
    const float* bq_att  = (const float*)d_in[5];
    const float* Wa      = (const float*)d_in[6];
    // d_in[7] = ba: constant over softmax axis -> cancels, unused.
    const float* Wf      = (const float*)d_in[8];
    const float* bf_     = (const float*)d_in[9];
    const float* Wqf     = (const float*)d_in[10];
    const float* bqf     = (const float*)d_in[11];
    const float* Wc      = (const float*)d_in[12];
    const float* bc      = (const float*)d_in[13];
    float* out = (float*)d_out;

    char* wsb = (char*)d_ws;
    size_t off = 0;
    auto carve = [&](size_t bytes) -> void* {
        void* p = wsb + off;
        off += (bytes + 255) & ~(size_t)255;
        return p;
    };
    __hip_bfloat16* vt  = (__hip_bfloat16*)carve((size_t)MROWS * DV * 2);   // 102.8 MB
    __hip_bfloat16* wvt = (__hip_bfloat16*)carve((size_t)DAP * DV * 2);     //   5.2 MB
    float* Cp       = (float*)carve((size_t)KSPLIT * 128 * NQ * 4);         //  13.6 MB
    float* scores_p = (float*)carve((size_t)NT * MROWS * GG * 4);           //   4.0 MB
    float* qatt = (float*)carve((size_t)BB * DAP * 4);
    float* qfus = (float*)carve((size_t)BB * DH * 4);
    float* bvp  = (float*)carve((size_t)DAP * 4);
    float* wap  = (float*)carve((size_t)DAP * GG * 4);
    float* vatt = (float*)carve((size_t)BB * GG * DV * 4);
    float* xbuf = (float*)carve((size_t)BB * DH * 4);
    (void)ws_size; (void)n_in; (void)in_sizes; (void)out_size;

    pad_misc<<<dim3(20), 256, 0, stream>>>(bv, Wa, bvp, wap);
    transpose_v<<<dim3(DV / 128, 4, BB), 256, 0, stream>>>(input_v, vt);
    transpose_w<<<dim3(DAP / 64, DV / 64), 256, 0, stream>>>(Wv, wvt);

    // merged q-branch GEMM (split-K fp32): cols [0,1280)=Wq_att, [1280,3328)=Wqf
    gemm_partial<2><<<dim3(NQ / 64, KSPLIT), 256, 0, stream>>>(
        x_q, DQ, Wq_att, Wqf, Cp, NQ);
    epilogue_q<<<dim3(NQ / 256, BB), 256, 0, stream>>>(Cp, bq_att, bqf, qatt, qfus);

    // big MFMA GEMM with fused score reduction -> scores_p (per-ntile partials)
    big_gemm<<<dim3(24 * 80 + 40), 256, 0, stream>>>(vt, wvt, bvp, qatt, wap, scores_p);

    // softmax over spatial + glimpse pooling -> vatt [128][4][2048]
    softmax_pool<<<dim3(4, BB), 256, 0, stream>>>(scores_p, vt, vatt);

    // glimpse fusion: xbuf = tanh(tanh(vatt@Wf + bf) * qfus)
    gemm_partial<1><<<dim3(DH / 64, KSPLIT), 256, 0, stream>>>(
        vatt, GG * DV, Wf, nullptr, Cp, DH);
    gemm_epilogue<2><<<dim3(DH / 256, BB), 256, 0, stream>>>(
        Cp, DH, DH, bf_, qfus, xbuf, DH);

    // classifier: out = xbuf @ Wc + bc
    gemm_partial<0><<<dim3(NANSP / 64, KSPLIT), 256, 0, stream>>>(
        xbuf, DH, Wc, nullptr, Cp, NANSP);
    gemm_epilogue<0><<<dim3(NANSP / 256 + 1, BB), 256, 0, stream>>>(
        Cp, NANSP, NANS, bc, nullptr, out, NANS);
}